// Round 9
// baseline (463.056 us; speedup 1.0000x reference)
//
#include <hip/hip_runtime.h>

typedef unsigned short UST;
typedef __bf16 bf16x8 __attribute__((ext_vector_type(8)));
typedef float floatx4 __attribute__((ext_vector_type(4)));
typedef unsigned short ushort8v __attribute__((ext_vector_type(8)));
typedef unsigned short ushort4v __attribute__((ext_vector_type(4)));

#define N_NODES 20000
#define E_EDGES 320000
#define KF 384         // edge-MLP K after hoisting hi/hj/le out: fd only (interleaved sin/cos)
#define M_PAD 20096    // 157*128 = 314*64

// fragment-order column permutation: orig col n -> (n&0xC0) | ((n&15)<<2) | ((n>>4)&3)
// so that the 4 values one lane needs (ni=0..3 at fixed lm) are contiguous.

static __device__ __forceinline__ UST f2bf(float x){
  unsigned int u = __float_as_uint(x);
  u += 0x7fffu + ((u >> 16) & 1u);   // round-to-nearest-even
  return (UST)(u >> 16);
}
static __device__ __forceinline__ float bf2f(UST u){
  return __uint_as_float(((unsigned int)u) << 16);
}
static __device__ __forceinline__ float bflo(unsigned u){ return __uint_as_float(u << 16); }
static __device__ __forceinline__ float bfhi(unsigned u){ return __uint_as_float(u & 0xffff0000u); }
// fast silu: v_rcp instead of full-precision divide; ~1ULP, invisible after bf16 rounding
static __device__ __forceinline__ float siluf(float v){
  return v * __builtin_amdgcn_rcpf(1.0f + __expf(-v));
}
// packed f32x2 -> bf16x2 (RNE), one VALU op
static __device__ __forceinline__ unsigned int cvtpk(float lo, float hi){
  unsigned int r;
  asm("v_cvt_pk_bf16_f32 %0, %1, %2" : "=v"(r) : "v"(lo), "v"(hi));
  return r;
}
// async global->LDS, 16B per lane; LDS dest must be wave-uniform base + lane*16
static __device__ __forceinline__ void gll16(const void* g, void* lds){
  __builtin_amdgcn_global_load_lds(
      (const __attribute__((address_space(1))) unsigned int*)g,
      (__attribute__((address_space(3))) unsigned int*)lds, 16, 0, 0);
}

// As: rows x 32 cols. Bs: 256 rows x 32 cols. Wave computes 64x64 at (wM,wN).
static __device__ __forceinline__ void mfma_step(const UST* As, const UST* Bs,
    floatx4 (&acc)[4][4], int lm, int quad, int wM, int wN){
  bf16x8 a[4], b[4];
#pragma unroll
  for (int i = 0; i < 4; ++i)
    a[i] = *(const bf16x8*)(As + (wM + i*16 + lm)*32 + quad*8);
#pragma unroll
  for (int i = 0; i < 4; ++i)
    b[i] = *(const bf16x8*)(Bs + (wN + i*16 + lm)*32 + quad*8);
#pragma unroll
  for (int mi = 0; mi < 4; ++mi)
#pragma unroll
    for (int ni = 0; ni < 4; ++ni)
      acc[mi][ni] = __builtin_amdgcn_mfma_f32_16x16x32_bf16(a[mi], b[ni], acc[mi][ni], 0, 0, 0);
}

// barrier-free K-loop: A from LDS tile [rows][ldA], B direct from global [rows][Kb]
static __device__ __forceinline__ void mfma_direct(const UST* At, int ldA,
    const UST* Bg, int Kb, int klen, floatx4 (&acc)[4][4], int lm, int quad, int wM, int wN){
#pragma unroll 2
  for (int k0 = 0; k0 < klen; k0 += 32){
    bf16x8 a[4], b[4];
#pragma unroll
    for (int i = 0; i < 4; ++i)
      a[i] = *(const bf16x8*)(At + (wM + i*16 + lm)*ldA + k0 + quad*8);
#pragma unroll
    for (int i = 0; i < 4; ++i)
      b[i] = *(const bf16x8*)(Bg + (size_t)(wN + i*16 + lm)*Kb + k0 + quad*8);
#pragma unroll
    for (int mi = 0; mi < 4; ++mi)
#pragma unroll
      for (int ni = 0; ni < 4; ++ni)
        acc[mi][ni] = __builtin_amdgcn_mfma_f32_16x16x32_bf16(a[mi], b[ni], acc[mi][ni], 0, 0, 0);
  }
}

// ---------------- fused prep: weights + LayerNorm + Pleb + edge histogram ----------------
__global__ __launch_bounds__(256) void prep_all(
    const float* __restrict__ We1, const float* __restrict__ We2,
    const float* __restrict__ Wn1, const float* __restrict__ Wn2,
    const float* __restrict__ x, const float* __restrict__ gamma,
    const float* __restrict__ beta, const float* __restrict__ lat,
    const int* __restrict__ esrc, const float* __restrict__ be1,
    int* __restrict__ cnti,
    UST* __restrict__ W1T, UST* __restrict__ W2T,
    UST* __restrict__ Wn1T, UST* __restrict__ Wn2T, UST* __restrict__ W1hT,
    UST* __restrict__ h, float* __restrict__ Pleb){
  int bid = blockIdx.x, t = threadIdx.x;
  if (bid < 384){                                   // W1T_fd [256 n][384 k]
    int i = bid*256 + t;
    int n = i / KF, k = i % KF;
    W1T[i] = f2bf(We1[(size_t)(521 + (k&1)*192 + (k>>1))*256 + n]);
  } else if (bid < 640){                            // W2T + Wn2T
    int i = (bid-384)*256 + t;
    int n = i >> 8, k = i & 255;
    W2T[i]  = f2bf(We2[(size_t)k*256 + n]);
    Wn2T[i] = f2bf(Wn2[(size_t)k*256 + n]);
  } else if (bid < 1152){                           // Wn1T [256 n][512 k]
    int i = (bid-640)*256 + t;
    int n = i >> 9, k = i & 511;
    Wn1T[i] = f2bf(Wn1[(size_t)k*256 + n]);
  } else if (bid < 1664){                           // W1hT [512 n][256 k]
    int n = bid - 1152, k = t;
    W1hT[n*256 + k] = f2bf(We1[(size_t)(k + (n & 256))*256 + (n & 255)]);
  } else if (bid < 6664){                           // LayerNorm, 4 rows/block
    int wave = t >> 6, lane = t & 63;
    int row = (bid-1664)*4 + wave;
    const float4* xp = (const float4*)(x + (size_t)row * 256);
    float4 v = xp[lane];
    float s  = v.x + v.y + v.z + v.w;
    float sq = v.x*v.x + v.y*v.y + v.z*v.z + v.w*v.w;
#pragma unroll
    for (int o = 32; o > 0; o >>= 1){ s += __shfl_xor(s, o); sq += __shfl_xor(sq, o); }
    float mu  = s * (1.0f/256.0f);
    float var = sq * (1.0f/256.0f) - mu*mu;
    float rs  = rsqrtf(var + 1e-5f);
    float4 g = ((const float4*)gamma)[lane];
    float4 b = ((const float4*)beta)[lane];
    uint2 o2;
    o2.x = cvtpk((v.x-mu)*rs*g.x + b.x, (v.y-mu)*rs*g.y + b.y);
    o2.y = cvtpk((v.z-mu)*rs*g.z + b.z, (v.w-mu)*rs*g.w + b.w);
    *(uint2*)(h + (size_t)row*256 + lane*4) = o2;
  } else if (bid < 7664){                           // Pleb = (L@L^T)@We1_le + be1 (fp32, perm cols)
    int g = bid - 6664;
    const float* L = lat + g*9;
    float acc = be1[t];
#pragma unroll
    for (int a = 0; a < 3; ++a)
#pragma unroll
      for (int b = 0; b < 3; ++b){
        float ltlv = L[a*3+0]*L[b*3+0] + L[a*3+1]*L[b*3+1] + L[a*3+2]*L[b*3+2];
        acc += ltlv * We1[(size_t)(512 + a*3 + b)*256 + t];
      }
    int tp = (t & 0xC0) | ((t & 15) << 2) | ((t >> 4) & 3);
    Pleb[g*256 + tp] = acc;
  } else {                                          // edge src histogram
    int e = (bid-7664)*256 + t;
    if (e < E_EDGES) atomicAdd(&cnti[esrc[e]], 1);
  }
}

// ---------------- CSR build: scan -> fill (+sorted srcs) ----------------
__global__ __launch_bounds__(256) void scan_kernel(const int* __restrict__ cnti,
    int* __restrict__ off, int* __restrict__ head){
  __shared__ int ps[256];
  int t = threadIdx.x;
  const int CH = 80;                       // 256*80 = 20480 >= 20000 (cnti padded)
  const int4* cp = (const int4*)cnti;
  int base = t * CH;
  int s = 0;
#pragma unroll 1
  for (int i = 0; i < CH/4; ++i){
    int4 v = cp[t*(CH/4) + i];
    int idx = base + i*4;
    if (idx   < N_NODES) s += v.x;
    if (idx+1 < N_NODES) s += v.y;
    if (idx+2 < N_NODES) s += v.z;
    if (idx+3 < N_NODES) s += v.w;
  }
  ps[t] = s; __syncthreads();
#pragma unroll 1
  for (int o = 1; o < 256; o <<= 1){
    int v = (t >= o) ? ps[t - o] : 0;
    __syncthreads();
    ps[t] += v;
    __syncthreads();
  }
  int run = (t > 0) ? ps[t-1] : 0;
#pragma unroll 1
  for (int i = 0; i < CH/4; ++i){
    int4 v = cp[t*(CH/4) + i];
    int idx = base + i*4;
    int a4[4] = {v.x, v.y, v.z, v.w};
#pragma unroll
    for (int j = 0; j < 4; ++j){
      int id = idx + j;
      if (id < N_NODES){ off[id] = run; head[id] = run; run += a4[j]; }
    }
  }
  if (t == 255) off[N_NODES] = run;
}

__global__ __launch_bounds__(256) void fill_kernel(const int* __restrict__ src,
    int* __restrict__ head, int* __restrict__ eidx, int* __restrict__ srcs){
  int e = blockIdx.x*256 + threadIdx.x;
  if (e < E_EDGES){
    int s = src[e];
    int p = atomicAdd(&head[s], 1);
    eidx[p] = e;
    srcs[p] = s;
  }
}

// ======== P1 = h @ [We1_hi || We1_hj] : [20096, 512 perm] bf16 (R6 staged version) ========
__global__ __launch_bounds__(256, 4)
void gemm_p1(const UST* __restrict__ h, const UST* __restrict__ B1,
             UST* __restrict__ P1){
  __shared__ __attribute__((aligned(16))) UST lds[20480];  // 40KB
  UST* As0 = lds;             // [64][32]
  UST* As1 = lds + 2048;
  UST* Bs0 = lds + 4096;      // [256][32]
  UST* Bs1 = lds + 12288;
  int t = threadIdx.x;
  int bM = blockIdx.x >> 1, bN = (blockIdx.x & 1) << 8;
  int rA = t >> 2, cA = (t & 3) * 8;
  const UST* hrow = h + (size_t)(bM*64 + rA)*256;
  int lane = t & 63, lm = lane & 15, quad = lane >> 4;
  int wave = t >> 6, wN = wave*64;
  floatx4 acc[4][4] = {};
  UST* a0d = &As0[rA*32 + cA];
  UST* a1d = &As1[rA*32 + cA];
#pragma unroll 1
  for (int w = 0; w < 4; ++w){
    int k0 = w*64;
    gll16(hrow + k0 + cA,      a0d);
    gll16(hrow + k0 + 32 + cA, a1d);
#pragma unroll
    for (int j = 0; j < 4; ++j){
      int rB = j*64 + rA;
      gll16(B1 + (size_t)(bN + rB)*256 + k0 + cA,      &Bs0[rB*32 + cA]);
      gll16(B1 + (size_t)(bN + rB)*256 + k0 + 32 + cA, &Bs1[rB*32 + cA]);
    }
    __syncthreads();
    mfma_step(As0, Bs0, acc, lm, quad, 0, wN);
    mfma_step(As1, Bs1, acc, lm, quad, 0, wN);
    __syncthreads();
  }
  int mbase = bM*64 + quad*4;
#pragma unroll
  for (int mi = 0; mi < 4; ++mi)
#pragma unroll
    for (int r = 0; r < 4; ++r){
      int m = mbase + mi*16 + r;
      uint2 v;
      v.x = cvtpk(acc[mi][0][r], acc[mi][1][r]);   // cols lm*4+0, +1
      v.y = cvtpk(acc[mi][2][r], acc[mi][3][r]);   // cols lm*4+2, +3
      *(uint2*)(P1 + (size_t)m*512 + bN + wN + lm*4) = v;   // fragment-order cols, bf16
    }
}

// ======== MEGA-KERNEL (R6 structure + trans-recurrence + setprio) ========
// Phase 1: 6 x 64-col windows, staged gll16 B, A built in-register.
//          A-build: per 4-angle group, 1 seed (fract+sin+cos) + 3 FMA rotations
//          (96 -> 30 transcendentals/thread; numerics HW-validated in R4/R5).
//          setprio(1) around the MFMA burst (2 independent blocks/CU arbitrate).
// Epilogue: acc += P1[src] + P1[dst]+256 (bf16) + Pleb[g] (fp32) -> silu -> e1t.
// Phase 2: e1t @ W2T direct-global, no barriers. Phase 3: EsT transpose + seg col sums.
__global__ __launch_bounds__(512, 4)
void gemm_edge_fused(const int* __restrict__ ei, const int* __restrict__ e2g,
                     const float* __restrict__ fdif, const UST* __restrict__ W1T,
                     const int* __restrict__ eidx,
                     const UST* __restrict__ W2T, const float* __restrict__ be2,
                     const int* __restrict__ rownode,
                     const UST* __restrict__ P1, const float* __restrict__ Pleb,
                     float* __restrict__ sums){
  __shared__ __attribute__((aligned(16))) UST lds[128*264];  // 67.6KB union
  __shared__ int rn[128], rd[128], rg[128];
  UST* As0 = lds;             // ph1 staging: 128*32 bf16
  UST* As1 = lds + 4096;
  UST* Bs0 = lds + 8192;      // ph1 staging: 256*32 bf16
  UST* Bs1 = lds + 16384;
  UST* e1t = lds;             // ph2: [128 rows][264 cols pad]
  UST* EsT = lds;             // ph3: [256 cols][132 rows pad]
  int t = threadIdx.x;
  int bM = blockIdx.x;
  int rA = t >> 2, cA = (t & 3) * 8;       // one A-row per thread, 8-ushort chunk
  int p0 = bM*128 + rA;
  int e0 = eidx[p0];
  float f0x = fdif[e0*3+0], f0y = fdif[e0*3+1], f0z = fdif[e0*3+2];
  size_t btb0 = (size_t)rA*KF + cA;        // W1T rows rA, rA+128
  size_t btb1 = btb0 + (size_t)128*KF;
  int lane = t & 63, lm = lane & 15, quad = lane >> 4;
  int wave = t >> 6, wM = (wave >> 2)*64, wN = (wave & 3)*64;
  floatx4 acc[4][4] = {};
  UST* a0d = &As0[rA*32 + cA];
  UST* a1d = &As1[rA*32 + cA];
  UST* b0d0 = &Bs0[rA*32 + cA];
  UST* b0d1 = &Bs0[(128+rA)*32 + cA];
  UST* b1d0 = &Bs1[rA*32 + cA];
  UST* b1d1 = &Bs1[(128+rA)*32 + cA];
  if (t < 128){
    int e = eidx[bM*128 + t];
    rn[t] = rownode[bM*128 + t];           // == ei[e] (src)
    rd[t] = ei[E_EDGES + e];               // dst
    rg[t] = e2g[e];                        // graph
  }

  // per-dim unit-rotation sin/cos (revolutions; fr in [0,1))
  float sdx = __builtin_amdgcn_sinf(f0x), cdx = __builtin_amdgcn_cosf(f0x);
  float sdy = __builtin_amdgcn_sinf(f0y), cdy = __builtin_amdgcn_cosf(f0y);
  float sdz = __builtin_amdgcn_sinf(f0z), cdz = __builtin_amdgcn_cosf(f0z);
  // 4 consecutive angles jb..jb+3 (dim-uniform: jb%4==0, dim boundary at 64):
  // 1 seed + 3 rotation steps. sin/cos pairs packed to bf16x2.
  auto grp = [&](int jb)->uint4 {
    int dim = jb >> 6;
    float fr = (dim == 0) ? f0x : ((dim == 1) ? f0y : f0z);
    float sd = (dim == 0) ? sdx : ((dim == 1) ? sdy : sdz);
    float cd = (dim == 0) ? cdx : ((dim == 1) ? cdy : cdz);
    float q  = __builtin_amdgcn_fractf(fr * (float)(jb & 63));
    float sn = __builtin_amdgcn_sinf(q);
    float cs = __builtin_amdgcn_cosf(q);
    uint4 o;
    o.x = cvtpk(sn, cs);
    float t2;
    t2 = fmaf(sn, cd, cs*sd); cs = fmaf(cs, cd, -sn*sd); sn = t2; o.y = cvtpk(sn, cs);
    t2 = fmaf(sn, cd, cs*sd); cs = fmaf(cs, cd, -sn*sd); sn = t2; o.z = cvtpk(sn, cs);
    t2 = fmaf(sn, cd, cs*sd); cs = fmaf(cs, cd, -sn*sd); sn = t2; o.w = cvtpk(sn, cs);
    return o;
  };

  // ---- phase 1: K-loop over fd embedding only (6 windows of 64) ----
#pragma unroll 1
  for (int w = 0; w < 6; ++w){
    int k0 = w*64;
    gll16(W1T + btb0 + k0,      b0d0);    // issue DMA before the VALU burst
    gll16(W1T + btb1 + k0,      b0d1);
    gll16(W1T + btb0 + k0 + 32, b1d0);
    gll16(W1T + btb1 + k0 + 32, b1d1);
    int jb0 = (k0 + cA) >> 1;             // 4 angles per half-window
    uint4 o0 = grp(jb0);
    uint4 o1 = grp(jb0 + 16);
    *(uint4*)a0d = o0;
    *(uint4*)a1d = o1;
    __syncthreads();
    __builtin_amdgcn_s_setprio(1);
    mfma_step(As0, Bs0, acc, lm, quad, wM, wN);
    mfma_step(As1, Bs1, acc, lm, quad, wM, wN);
    __builtin_amdgcn_s_setprio(0);
    __syncthreads();                      // staging reads done; safe to overwrite / repurpose
  }

  // phase-1 epilogue: acc + gathered partials (P1 bf16 uint2, Pleb float4) -> silu -> e1t
#pragma unroll
  for (int mi = 0; mi < 4; ++mi){
    int ml0 = wM + mi*16 + quad*4;
    float bs[4][4];
#pragma unroll
    for (int r = 0; r < 4; ++r){
      int ml = ml0 + r;
      uint2 a2 = *(const uint2*)(P1 + (size_t)rn[ml]*512 + wN + lm*4);
      uint2 b2 = *(const uint2*)(P1 + (size_t)rd[ml]*512 + 256 + wN + lm*4);
      float4 c4 = *(const float4*)(Pleb + (size_t)rg[ml]*256 + wN + lm*4);
      bs[r][0] = bflo(a2.x) + bflo(b2.x) + c4.x;
      bs[r][1] = bfhi(a2.x) + bfhi(b2.x) + c4.y;
      bs[r][2] = bflo(a2.y) + bflo(b2.y) + c4.z;
      bs[r][3] = bfhi(a2.y) + bfhi(b2.y) + c4.w;
    }
#pragma unroll
    for (int ni = 0; ni < 4; ++ni){
      int nl = wN + ni*16 + lm;
      float f0 = siluf(acc[mi][ni][0] + bs[0][ni]);
      float f1 = siluf(acc[mi][ni][1] + bs[1][ni]);
      float f2 = siluf(acc[mi][ni][2] + bs[2][ni]);
      float f3 = siluf(acc[mi][ni][3] + bs[3][ni]);
      unsigned w01 = cvtpk(f0, f1);
      unsigned w23 = cvtpk(f2, f3);
      e1t[(ml0+0)*264 + nl] = (UST)(w01 & 0xffffu);
      e1t[(ml0+1)*264 + nl] = (UST)(w01 >> 16);
      e1t[(ml0+2)*264 + nl] = (UST)(w23 & 0xffffu);
      e1t[(ml0+3)*264 + nl] = (UST)(w23 >> 16);
    }
  }
  __syncthreads();

  // ---- phase 2: barrier-free K-loop, A from e1t, B from global W2T ----
  floatx4 acc2[4][4] = {};
  mfma_direct(e1t, 264, W2T, 256, 256, acc2, lm, quad, wM, wN);
  __syncthreads();   // e1t reads done; union becomes EsT

  // ---- phase 3: silu + transpose-store to EsT, 2-half segmented col sums ----
#pragma unroll
  for (int mi = 0; mi < 4; ++mi)
#pragma unroll
    for (int ni = 0; ni < 4; ++ni){
      int nl = wN + ni*16 + lm;
      int ml = wM + mi*16 + quad*4;
      float b = be2[nl];
      uint2 pk2;
      pk2.x = cvtpk(siluf(acc2[mi][ni][0] + b), siluf(acc2[mi][ni][1] + b));
      pk2.y = cvtpk(siluf(acc2[mi][ni][2] + b), siluf(acc2[mi][ni][3] + b));
      *(uint2*)&EsT[nl*132 + ml] = pk2;
    }
  __syncthreads();
  {
    int c = t & 255, hh = t >> 8;        // all 512 threads: (col, row-half)
    int rbeg = hh * 64;
    int cur = rn[rbeg];
    float run = 0.0f;
#pragma unroll 1
    for (int r = rbeg; r < rbeg + 64; r += 4){
      ushort4v v4 = *(const ushort4v*)&EsT[c*132 + r];
#pragma unroll
      for (int q2 = 0; q2 < 4; ++q2){
        int nd = rn[r + q2];
        if (nd != cur){ atomicAdd(&sums[(size_t)cur*256 + c], run); run = 0.0f; cur = nd; }
        run += bf2f(v4[q2]);
      }
    }
    atomicAdd(&sums[(size_t)cur*256 + c], run);
  }
}

// ======== fused node MLP1 + MLP2 (R6 staged version, 64-row tiles, 314 blocks) ========
__global__ __launch_bounds__(256, 4)
void gemm_node12(const UST* __restrict__ h, const float* __restrict__ sums,
                 const int* __restrict__ offs, const UST* __restrict__ B1,
                 const float* __restrict__ bn1, const UST* __restrict__ B2,
                 const float* __restrict__ bn2,
                 float* __restrict__ out_f, const float* __restrict__ resid){
  __shared__ __attribute__((aligned(16))) UST lds[20480];  // 40KB union
  UST* As0 = lds;             // [64][32]
  UST* As1 = lds + 2048;
  UST* Bs0 = lds + 4096;      // [256][32]
  UST* Bs1 = lds + 12288;
  UST* y1t = lds;             // [64][264]
  int t = threadIdx.x;
  int bM = blockIdx.x;
  int rA = t >> 2, cA = (t & 3) * 8;
  int row = bM*64 + rA;
  bool valid = row < N_NODES;
  float inv = 0.0f;
  if (valid){
    int deg = offs[row+1] - offs[row];
    inv = 1.0f / fmaxf((float)deg, 1.0f);
  }
  const UST* hrow = h + (size_t)row*256;
  const float* srow = sums + (size_t)row*256;
  int lane = t & 63, lm = lane & 15, quad = lane >> 4;
  int wave = t >> 6, wN = wave*64;
  floatx4 acc[4][4] = {};
  UST* a0d = &As0[rA*32 + cA];
  UST* a1d = &As1[rA*32 + cA];
  const uint4 z4 = {0,0,0,0};
#pragma unroll 1
  for (int w = 0; w < 8; ++w){
    int k0 = w*64;
    if (k0 < 256){                      // h half via async copy
      if (valid){
        gll16(hrow + k0 + cA,      a0d);
        gll16(hrow + k0 + 32 + cA, a1d);
      } else {
        *(uint4*)a0d = z4;
        *(uint4*)a1d = z4;
      }
    } else {                            // agg half built from sums/deg
      uint4 o0 = z4, o1 = z4;
      if (valid){
        int q = k0 - 256 + cA;
        float4 s0 = *(const float4*)(srow + q);
        float4 s1 = *(const float4*)(srow + q + 4);
        o0.x = cvtpk(s0.x*inv, s0.y*inv); o0.y = cvtpk(s0.z*inv, s0.w*inv);
        o0.z = cvtpk(s1.x*inv, s1.y*inv); o0.w = cvtpk(s1.z*inv, s1.w*inv);
        float4 s2 = *(const float4*)(srow + q + 32);
        float4 s3 = *(const float4*)(srow + q + 36);
        o1.x = cvtpk(s2.x*inv, s2.y*inv); o1.y = cvtpk(s2.z*inv, s2.w*inv);
        o1.z = cvtpk(s3.x*inv, s3.y*inv); o1.w = cvtpk(s3.z*inv, s3.w*inv);
      }
      *(uint4*)a0d = o0;
      *(uint4*)a1d = o1;
    }
#pragma unroll
    for (int j = 0; j < 4; ++j){
      int rB = j*64 + rA;
      gll16(B1 + (size_t)rB*512 + k0 + cA,      &Bs0[rB*32 + cA]);
      gll16(B1 + (size_t)rB*512 + k0 + 32 + cA, &Bs1[rB*32 + cA]);
    }
    __syncthreads();
    mfma_step(As0, Bs0, acc, lm, quad, 0, wN);
    mfma_step(As1, Bs1, acc, lm, quad, 0, wN);
    __syncthreads();
  }
  // epilogue 1: silu -> y1t (packed pairs over r)
#pragma unroll
  for (int mi = 0; mi < 4; ++mi){
    int ml0 = mi*16 + quad*4;
#pragma unroll
    for (int ni = 0; ni < 4; ++ni){
      int nl = wN + ni*16 + lm;
      float b = bn1[nl];
      unsigned w01 = cvtpk(siluf(acc[mi][ni][0] + b), siluf(acc[mi][ni][1] + b));
      unsigned w23 = cvtpk(siluf(acc[mi][ni][2] + b), siluf(acc[mi][ni][3] + b));
      y1t[(ml0+0)*264 + nl] = (UST)(w01 & 0xffffu);
      y1t[(ml0+1)*264 + nl] = (UST)(w01 >> 16);
      y1t[(ml0+2)*264 + nl] = (UST)(w23 & 0xffffu);
      y1t[(ml0+3)*264 + nl] = (UST)(w23 >> 16);
    }
  }
  __syncthreads();
  // phase 2: barrier-free
  floatx4 acc2[4][4] = {};
  mfma_direct(y1t, 264, B2, 256, 256, acc2, lm, quad, 0, wN);
  int mbase = bM*64 + quad*4;
  int nbase = wN + lm;
#pragma unroll
  for (int mi = 0; mi < 4; ++mi)
#pragma unroll
    for (int r = 0; r < 4; ++r){
      int m = mbase + mi*16 + r;
      if (m < N_NODES){
#pragma unroll
        for (int ni = 0; ni < 4; ++ni){
          int n = nbase + ni*16;
          float v = siluf(acc2[mi][ni][r] + bn2[n]);
          out_f[(size_t)m*256 + n] = resid[(size_t)m*256 + n] + v;
        }
      }
    }
}

extern "C" void kernel_launch(void* const* d_in, const int* in_sizes, int n_in,
                              void* d_out, int out_size, void* d_ws, size_t ws_size,
                              hipStream_t stream){
  (void)in_sizes; (void)n_in; (void)out_size; (void)ws_size;
  const float* node_features = (const float*)d_in[0];
  const float* lattices      = (const float*)d_in[1];
  const int*   edge_index    = (const int*)d_in[2];   // [2,E]: row0=src, row1=dst
  const int*   edge2graph    = (const int*)d_in[3];
  const float* frac_diff     = (const float*)d_in[4];
  const float* ln_gamma      = (const float*)d_in[6];
  const float* ln_beta       = (const float*)d_in[7];
  const float* We1 = (const float*)d_in[8];
  const float* be1 = (const float*)d_in[9];
  const float* We2 = (const float*)d_in[10];
  const float* be2 = (const float*)d_in[11];
  const float* Wn1 = (const float*)d_in[12];
  const float* bn1 = (const float*)d_in[13];
  const float* Wn2 = (const float*)d_in[14];
  const float* bn2 = (const float*)d_in[15];

  char* w = (char*)d_ws;
  size_t off_b = 0;
  auto carve = [&](size_t bytes) -> char* {
    char* p = w + off_b; off_b += (bytes + 1023) & ~(size_t)1023; return p;
  };
  UST*   W1T  = (UST*)carve((size_t)256*KF*2);
  UST*   W2T  = (UST*)carve((size_t)256*256*2);
  UST*   Wn1T = (UST*)carve((size_t)256*512*2);
  UST*   Wn2T = (UST*)carve((size_t)256*256*2);
  UST*   W1hT = (UST*)carve((size_t)512*256*2);
  UST*   hbf  = (UST*)carve((size_t)M_PAD*256*2);      // padded rows for gemm_p1
  UST*   P1   = (UST*)carve((size_t)M_PAD*512*2);      // [node][hi | hj] bf16, fragment cols
  float* Pleb = (float*)carve((size_t)1000*256*4);     // le contribution + be1, fp32, frag cols
  int*   cnti = (int*)carve((size_t)20480*4);          // padded for int4 scan
  int*   offs = (int*)carve((size_t)(N_NODES+1)*4);
  int*   head = (int*)carve((size_t)N_NODES*4);
  int*   eidx = (int*)carve((size_t)E_EDGES*4);
  int*   srcs = (int*)carve((size_t)E_EDGES*4);        // sorted src per CSR slot
  float* sums = (float*)carve((size_t)N_NODES*256*4);

  hipMemsetAsync(cnti, 0, (size_t)20480*4, stream);
  hipMemsetAsync(sums, 0, (size_t)N_NODES*256*4, stream);

  prep_all<<<7664 + E_EDGES/256, 256, 0, stream>>>(We1, We2, Wn1, Wn2,
      node_features, ln_gamma, ln_beta, lattices, edge_index, be1, cnti,
      W1T, W2T, Wn1T, Wn2T, W1hT, hbf, Pleb);

  scan_kernel<<<1, 256, 0, stream>>>(cnti, offs, head);
  fill_kernel<<<E_EDGES/256, 256, 0, stream>>>(edge_index, head, eidx, srcs);

  gemm_p1<<<(M_PAD/64)*2, 256, 0, stream>>>(hbf, W1hT, P1);

  gemm_edge_fused<<<E_EDGES/128, 512, 0, stream>>>(
      edge_index, edge2graph, frac_diff, W1T, eidx, W2T, be2, srcs, P1, Pleb, sums);

  gemm_node12<<<M_PAD/64, 256, 0, stream>>>(
      hbf, sums, offs, Wn1T, bn1, Wn2T, bn2, (float*)d_out, node_features);
}

// Round 10
// 406.971 us; speedup vs baseline: 1.1378x; 1.1378x over previous
//
#include <hip/hip_runtime.h>

typedef unsigned short UST;
typedef __bf16 bf16x8 __attribute__((ext_vector_type(8)));
typedef float floatx4 __attribute__((ext_vector_type(4)));
typedef unsigned short ushort8v __attribute__((ext_vector_type(8)));
typedef unsigned short ushort4v __attribute__((ext_vector_type(4)));

#define N_NODES 20000
#define E_EDGES 320000
#define KF 384         // edge-MLP K after hoisting hi/hj/le out: fd only (interleaved sin/cos)
#define M_PAD 20096    // 157*128 = 314*64

// fragment-order column permutation: orig col n -> (n&0xC0) | ((n&15)<<2) | ((n>>4)&3)
// so that the 4 values one lane needs (ni=0..3 at fixed lm) are contiguous.

static __device__ __forceinline__ UST f2bf(float x){
  unsigned int u = __float_as_uint(x);
  u += 0x7fffu + ((u >> 16) & 1u);   // round-to-nearest-even
  return (UST)(u >> 16);
}
static __device__ __forceinline__ float bf2f(UST u){
  return __uint_as_float(((unsigned int)u) << 16);
}
static __device__ __forceinline__ float bflo(unsigned u){ return __uint_as_float(u << 16); }
static __device__ __forceinline__ float bfhi(unsigned u){ return __uint_as_float(u & 0xffff0000u); }
// fast silu: v_rcp instead of full-precision divide; ~1ULP, invisible after bf16 rounding
static __device__ __forceinline__ float siluf(float v){
  return v * __builtin_amdgcn_rcpf(1.0f + __expf(-v));
}
// packed f32x2 -> bf16x2 (RNE), one VALU op
static __device__ __forceinline__ unsigned int cvtpk(float lo, float hi){
  unsigned int r;
  asm("v_cvt_pk_bf16_f32 %0, %1, %2" : "=v"(r) : "v"(lo), "v"(hi));
  return r;
}
// async global->LDS, 16B per lane; LDS dest must be wave-uniform base + lane*16
static __device__ __forceinline__ void gll16(const void* g, void* lds){
  __builtin_amdgcn_global_load_lds(
      (const __attribute__((address_space(1))) unsigned int*)g,
      (__attribute__((address_space(3))) unsigned int*)lds, 16, 0, 0);
}

// As: rows x 32 cols. Bs: 256 rows x 32 cols. Wave computes 64x64 at (wM,wN).
static __device__ __forceinline__ void mfma_step(const UST* As, const UST* Bs,
    floatx4 (&acc)[4][4], int lm, int quad, int wM, int wN){
  bf16x8 a[4], b[4];
#pragma unroll
  for (int i = 0; i < 4; ++i)
    a[i] = *(const bf16x8*)(As + (wM + i*16 + lm)*32 + quad*8);
#pragma unroll
  for (int i = 0; i < 4; ++i)
    b[i] = *(const bf16x8*)(Bs + (wN + i*16 + lm)*32 + quad*8);
#pragma unroll
  for (int mi = 0; mi < 4; ++mi)
#pragma unroll
    for (int ni = 0; ni < 4; ++ni)
      acc[mi][ni] = __builtin_amdgcn_mfma_f32_16x16x32_bf16(a[mi], b[ni], acc[mi][ni], 0, 0, 0);
}

// barrier-free K-loop: A from LDS tile [rows][ldA], B direct from global [256][Kb]
static __device__ __forceinline__ void mfma_direct(const UST* At, int ldA,
    const UST* Bg, int Kb, int klen, floatx4 (&acc)[4][4], int lm, int quad, int wM, int wN){
#pragma unroll 2
  for (int k0 = 0; k0 < klen; k0 += 32){
    bf16x8 a[4], b[4];
#pragma unroll
    for (int i = 0; i < 4; ++i)
      a[i] = *(const bf16x8*)(At + (wM + i*16 + lm)*ldA + k0 + quad*8);
#pragma unroll
    for (int i = 0; i < 4; ++i)
      b[i] = *(const bf16x8*)(Bg + (size_t)(wN + i*16 + lm)*Kb + k0 + quad*8);
#pragma unroll
    for (int mi = 0; mi < 4; ++mi)
#pragma unroll
      for (int ni = 0; ni < 4; ++ni)
        acc[mi][ni] = __builtin_amdgcn_mfma_f32_16x16x32_bf16(a[mi], b[ni], acc[mi][ni], 0, 0, 0);
  }
}

// ---------------- fused prep: weights + LayerNorm + Pleb + edge histogram ----------------
__global__ __launch_bounds__(256) void prep_all(
    const float* __restrict__ We1, const float* __restrict__ We2,
    const float* __restrict__ Wn1, const float* __restrict__ Wn2,
    const float* __restrict__ x, const float* __restrict__ gamma,
    const float* __restrict__ beta, const float* __restrict__ lat,
    const int* __restrict__ esrc, const float* __restrict__ be1,
    int* __restrict__ cnti,
    UST* __restrict__ W1T, UST* __restrict__ W2T,
    UST* __restrict__ Wn1T, UST* __restrict__ Wn2T, UST* __restrict__ W1hT,
    UST* __restrict__ h, float* __restrict__ Pleb){
  int bid = blockIdx.x, t = threadIdx.x;
  if (bid < 384){                                   // W1T_fd [256 n][384 k]
    int i = bid*256 + t;
    int n = i / KF, k = i % KF;
    W1T[i] = f2bf(We1[(size_t)(521 + (k&1)*192 + (k>>1))*256 + n]);
  } else if (bid < 640){                            // W2T + Wn2T
    int i = (bid-384)*256 + t;
    int n = i >> 8, k = i & 255;
    W2T[i]  = f2bf(We2[(size_t)k*256 + n]);
    Wn2T[i] = f2bf(Wn2[(size_t)k*256 + n]);
  } else if (bid < 1152){                           // Wn1T [256 n][512 k]
    int i = (bid-640)*256 + t;
    int n = i >> 9, k = i & 511;
    Wn1T[i] = f2bf(Wn1[(size_t)k*256 + n]);
  } else if (bid < 1664){                           // W1hT [512 n][256 k]
    int n = bid - 1152, k = t;
    W1hT[n*256 + k] = f2bf(We1[(size_t)(k + (n & 256))*256 + (n & 255)]);
  } else if (bid < 6664){                           // LayerNorm, 4 rows/block
    int wave = t >> 6, lane = t & 63;
    int row = (bid-1664)*4 + wave;
    const float4* xp = (const float4*)(x + (size_t)row * 256);
    float4 v = xp[lane];
    float s  = v.x + v.y + v.z + v.w;
    float sq = v.x*v.x + v.y*v.y + v.z*v.z + v.w*v.w;
#pragma unroll
    for (int o = 32; o > 0; o >>= 1){ s += __shfl_xor(s, o); sq += __shfl_xor(sq, o); }
    float mu  = s * (1.0f/256.0f);
    float var = sq * (1.0f/256.0f) - mu*mu;
    float rs  = rsqrtf(var + 1e-5f);
    float4 g = ((const float4*)gamma)[lane];
    float4 b = ((const float4*)beta)[lane];
    uint2 o2;
    o2.x = cvtpk((v.x-mu)*rs*g.x + b.x, (v.y-mu)*rs*g.y + b.y);
    o2.y = cvtpk((v.z-mu)*rs*g.z + b.z, (v.w-mu)*rs*g.w + b.w);
    *(uint2*)(h + (size_t)row*256 + lane*4) = o2;
  } else if (bid < 7664){                           // Pleb = (L@L^T)@We1_le + be1 (fp32, perm cols)
    int g = bid - 6664;
    const float* L = lat + g*9;
    float acc = be1[t];
#pragma unroll
    for (int a = 0; a < 3; ++a)
#pragma unroll
      for (int b = 0; b < 3; ++b){
        float ltlv = L[a*3+0]*L[b*3+0] + L[a*3+1]*L[b*3+1] + L[a*3+2]*L[b*3+2];
        acc += ltlv * We1[(size_t)(512 + a*3 + b)*256 + t];
      }
    int tp = (t & 0xC0) | ((t & 15) << 2) | ((t >> 4) & 3);
    Pleb[g*256 + tp] = acc;
  } else {                                          // edge src histogram
    int e = (bid-7664)*256 + t;
    if (e < E_EDGES) atomicAdd(&cnti[esrc[e]], 1);
  }
}

// ---------------- CSR build: scan -> fill (+sorted srcs) ----------------
__global__ __launch_bounds__(256) void scan_kernel(const int* __restrict__ cnti,
    int* __restrict__ off, int* __restrict__ head){
  __shared__ int ps[256];
  int t = threadIdx.x;
  const int CH = 80;                       // 256*80 = 20480 >= 20000 (cnti padded)
  const int4* cp = (const int4*)cnti;
  int base = t * CH;
  int s = 0;
#pragma unroll 1
  for (int i = 0; i < CH/4; ++i){
    int4 v = cp[t*(CH/4) + i];
    int idx = base + i*4;
    if (idx   < N_NODES) s += v.x;
    if (idx+1 < N_NODES) s += v.y;
    if (idx+2 < N_NODES) s += v.z;
    if (idx+3 < N_NODES) s += v.w;
  }
  ps[t] = s; __syncthreads();
#pragma unroll 1
  for (int o = 1; o < 256; o <<= 1){
    int v = (t >= o) ? ps[t - o] : 0;
    __syncthreads();
    ps[t] += v;
    __syncthreads();
  }
  int run = (t > 0) ? ps[t-1] : 0;
#pragma unroll 1
  for (int i = 0; i < CH/4; ++i){
    int4 v = cp[t*(CH/4) + i];
    int idx = base + i*4;
    int a4[4] = {v.x, v.y, v.z, v.w};
#pragma unroll
    for (int j = 0; j < 4; ++j){
      int id = idx + j;
      if (id < N_NODES){ off[id] = run; head[id] = run; run += a4[j]; }
    }
  }
  if (t == 255) off[N_NODES] = run;
}

__global__ __launch_bounds__(256) void fill_kernel(const int* __restrict__ src,
    int* __restrict__ head, int* __restrict__ eidx, int* __restrict__ srcs){
  int e = blockIdx.x*256 + threadIdx.x;
  if (e < E_EDGES){
    int s = src[e];
    int p = atomicAdd(&head[s], 1);
    eidx[p] = e;
    srcs[p] = s;
  }
}

// ======== P1 = h @ [We1_hi || We1_hj] : [20096, 512 perm] bf16 (per-node MLP1 partials) ========
// 64-row x 256-col tiles, 256 threads / 4 waves, 628 blocks. Cols in fragment order, bf16-packed.
__global__ __launch_bounds__(256, 4)
void gemm_p1(const UST* __restrict__ h, const UST* __restrict__ B1,
             UST* __restrict__ P1){
  __shared__ __attribute__((aligned(16))) UST lds[20480];  // 40KB
  UST* As0 = lds;             // [64][32]
  UST* As1 = lds + 2048;
  UST* Bs0 = lds + 4096;      // [256][32]
  UST* Bs1 = lds + 12288;
  int t = threadIdx.x;
  int bM = blockIdx.x >> 1, bN = (blockIdx.x & 1) << 8;
  int rA = t >> 2, cA = (t & 3) * 8;
  const UST* hrow = h + (size_t)(bM*64 + rA)*256;
  int lane = t & 63, lm = lane & 15, quad = lane >> 4;
  int wave = t >> 6, wN = wave*64;
  floatx4 acc[4][4] = {};
  UST* a0d = &As0[rA*32 + cA];
  UST* a1d = &As1[rA*32 + cA];
#pragma unroll 1
  for (int w = 0; w < 4; ++w){
    int k0 = w*64;
    gll16(hrow + k0 + cA,      a0d);
    gll16(hrow + k0 + 32 + cA, a1d);
#pragma unroll
    for (int j = 0; j < 4; ++j){
      int rB = j*64 + rA;
      gll16(B1 + (size_t)(bN + rB)*256 + k0 + cA,      &Bs0[rB*32 + cA]);
      gll16(B1 + (size_t)(bN + rB)*256 + k0 + 32 + cA, &Bs1[rB*32 + cA]);
    }
    __syncthreads();
    mfma_step(As0, Bs0, acc, lm, quad, 0, wN);
    mfma_step(As1, Bs1, acc, lm, quad, 0, wN);
    __syncthreads();
  }
  int mbase = bM*64 + quad*4;
#pragma unroll
  for (int mi = 0; mi < 4; ++mi)
#pragma unroll
    for (int r = 0; r < 4; ++r){
      int m = mbase + mi*16 + r;
      uint2 v;
      v.x = cvtpk(acc[mi][0][r], acc[mi][1][r]);   // cols lm*4+0, +1
      v.y = cvtpk(acc[mi][2][r], acc[mi][3][r]);   // cols lm*4+2, +3
      *(uint2*)(P1 + (size_t)m*512 + bN + wN + lm*4) = v;   // fragment-order cols, bf16
    }
}

// ======== MEGA-KERNEL (best-known state, 208us): edge MLP1 + MLP2 + scatter ========
// Phase 1: acc = fd_emb @ W1T_fd (K=384, sin/cos generated in-register into LDS A-tiles).
//          Epilogue: acc += P1[src] + P1[dst]+256 (bf16 uint2) + Pleb[g] (float4) -> silu -> e1t.
// Phase 2: e2 = e1t @ W2T, A-frags from LDS, B-frags direct global, no barriers.
// Phase 3: silu -> EsT col-major LDS -> 2-half segmented col sums -> atomicAdd sums.
__global__ __launch_bounds__(512, 4)
void gemm_edge_fused(const int* __restrict__ ei, const int* __restrict__ e2g,
                     const float* __restrict__ fdif, const UST* __restrict__ W1T,
                     const int* __restrict__ eidx,
                     const UST* __restrict__ W2T, const float* __restrict__ be2,
                     const int* __restrict__ rownode,
                     const UST* __restrict__ P1, const float* __restrict__ Pleb,
                     float* __restrict__ sums){
  __shared__ __attribute__((aligned(16))) UST lds[128*264];  // 67.6KB union
  __shared__ int rn[128], rd[128], rg[128];
  UST* As0 = lds;             // ph1 staging: 128*32 bf16
  UST* As1 = lds + 4096;
  UST* Bs0 = lds + 8192;      // ph1 staging: 256*32 bf16
  UST* Bs1 = lds + 16384;
  UST* e1t = lds;             // ph2: [128 rows][264 cols pad]
  UST* EsT = lds;             // ph3: [256 cols][132 rows pad]
  int t = threadIdx.x;
  int bM = blockIdx.x;
  int rA = t >> 2, cA = (t & 3) * 8;       // one A-row per thread, 8-ushort chunk
  int p0 = bM*128 + rA;
  int e0 = eidx[p0];
  float f0x = fdif[e0*3+0], f0y = fdif[e0*3+1], f0z = fdif[e0*3+2];
  size_t btb0 = (size_t)rA*KF + cA;        // W1T rows rA, rA+128
  size_t btb1 = btb0 + (size_t)128*KF;
  int lane = t & 63, lm = lane & 15, quad = lane >> 4;
  int wave = t >> 6, wM = (wave >> 2)*64, wN = (wave & 3)*64;
  floatx4 acc[4][4] = {};
  UST* a0d = &As0[rA*32 + cA];
  UST* a1d = &As1[rA*32 + cA];
  UST* b0d0 = &Bs0[rA*32 + cA];
  UST* b0d1 = &Bs0[(128+rA)*32 + cA];
  UST* b1d0 = &Bs1[rA*32 + cA];
  UST* b1d1 = &Bs1[(128+rA)*32 + cA];
  if (t < 128){
    int e = eidx[bM*128 + t];
    rn[t] = rownode[bM*128 + t];           // == ei[e] (src)
    rd[t] = ei[E_EDGES + e];               // dst
    rg[t] = e2g[e];                        // graph
  }

  // ---- phase 1: K-loop over fd embedding only (6 windows of 64) ----
#pragma unroll 1
  for (int w = 0; w < 6; ++w){
    int k0 = w*64;
    gll16(W1T + btb0 + k0,      b0d0);    // issue DMA before the VALU burst
    gll16(W1T + btb1 + k0,      b0d1);
    gll16(W1T + btb0 + k0 + 32, b1d0);
    gll16(W1T + btb1 + k0 + 32, b1d1);
    int jb0 = (k0 + cA) >> 1;             // 4 angles per half-window
    uint4 o0, o1;
    unsigned w0[4], w1[4];
#pragma unroll
    for (int ii = 0; ii < 4; ++ii){
      int jj = jb0 + ii;
      int dim = jj >> 6; float kf = (float)(jj & 63);
      float fr = (dim == 0) ? f0x : ((dim == 1) ? f0y : f0z);
      float q = __builtin_amdgcn_fractf(fr * kf);
      w0[ii] = cvtpk(__builtin_amdgcn_sinf(q), __builtin_amdgcn_cosf(q));
    }
#pragma unroll
    for (int ii = 0; ii < 4; ++ii){
      int jj = jb0 + 16 + ii;
      int dim = jj >> 6; float kf = (float)(jj & 63);
      float fr = (dim == 0) ? f0x : ((dim == 1) ? f0y : f0z);
      float q = __builtin_amdgcn_fractf(fr * kf);
      w1[ii] = cvtpk(__builtin_amdgcn_sinf(q), __builtin_amdgcn_cosf(q));
    }
    o0.x = w0[0]; o0.y = w0[1]; o0.z = w0[2]; o0.w = w0[3];
    o1.x = w1[0]; o1.y = w1[1]; o1.z = w1[2]; o1.w = w1[3];
    *(uint4*)a0d = o0;
    *(uint4*)a1d = o1;
    __syncthreads();
    mfma_step(As0, Bs0, acc, lm, quad, wM, wN);
    mfma_step(As1, Bs1, acc, lm, quad, wM, wN);
    __syncthreads();                      // staging reads done; safe to overwrite / repurpose
  }

  // phase-1 epilogue: acc + gathered partials (P1 bf16 uint2, Pleb float4) -> silu -> e1t
#pragma unroll
  for (int mi = 0; mi < 4; ++mi){
    int ml0 = wM + mi*16 + quad*4;
    float bs[4][4];
#pragma unroll
    for (int r = 0; r < 4; ++r){
      int ml = ml0 + r;
      uint2 a2 = *(const uint2*)(P1 + (size_t)rn[ml]*512 + wN + lm*4);
      uint2 b2 = *(const uint2*)(P1 + (size_t)rd[ml]*512 + 256 + wN + lm*4);
      float4 c4 = *(const float4*)(Pleb + (size_t)rg[ml]*256 + wN + lm*4);
      bs[r][0] = bflo(a2.x) + bflo(b2.x) + c4.x;
      bs[r][1] = bfhi(a2.x) + bfhi(b2.x) + c4.y;
      bs[r][2] = bflo(a2.y) + bflo(b2.y) + c4.z;
      bs[r][3] = bfhi(a2.y) + bfhi(b2.y) + c4.w;
    }
#pragma unroll
    for (int ni = 0; ni < 4; ++ni){
      int nl = wN + ni*16 + lm;
      float f0 = siluf(acc[mi][ni][0] + bs[0][ni]);
      float f1 = siluf(acc[mi][ni][1] + bs[1][ni]);
      float f2 = siluf(acc[mi][ni][2] + bs[2][ni]);
      float f3 = siluf(acc[mi][ni][3] + bs[3][ni]);
      unsigned w01 = cvtpk(f0, f1);
      unsigned w23 = cvtpk(f2, f3);
      e1t[(ml0+0)*264 + nl] = (UST)(w01 & 0xffffu);
      e1t[(ml0+1)*264 + nl] = (UST)(w01 >> 16);
      e1t[(ml0+2)*264 + nl] = (UST)(w23 & 0xffffu);
      e1t[(ml0+3)*264 + nl] = (UST)(w23 >> 16);
    }
  }
  __syncthreads();

  // ---- phase 2: barrier-free K-loop, A from e1t, B from global W2T ----
  floatx4 acc2[4][4] = {};
  mfma_direct(e1t, 264, W2T, 256, 256, acc2, lm, quad, wM, wN);
  __syncthreads();   // e1t reads done; union becomes EsT

  // ---- phase 3: silu + transpose-store to EsT, 2-half segmented col sums ----
#pragma unroll
  for (int mi = 0; mi < 4; ++mi)
#pragma unroll
    for (int ni = 0; ni < 4; ++ni){
      int nl = wN + ni*16 + lm;
      int ml = wM + mi*16 + quad*4;
      float b = be2[nl];
      uint2 pk2;
      pk2.x = cvtpk(siluf(acc2[mi][ni][0] + b), siluf(acc2[mi][ni][1] + b));
      pk2.y = cvtpk(siluf(acc2[mi][ni][2] + b), siluf(acc2[mi][ni][3] + b));
      *(uint2*)&EsT[nl*132 + ml] = pk2;
    }
  __syncthreads();
  {
    int c = t & 255, hh = t >> 8;        // all 512 threads: (col, row-half)
    int rbeg = hh * 64;
    int cur = rn[rbeg];
    float run = 0.0f;
#pragma unroll 1
    for (int r = rbeg; r < rbeg + 64; r += 4){
      ushort4v v4 = *(const ushort4v*)&EsT[c*132 + r];
#pragma unroll
      for (int q2 = 0; q2 < 4; ++q2){
        int nd = rn[r + q2];
        if (nd != cur){ atomicAdd(&sums[(size_t)cur*256 + c], run); run = 0.0f; cur = nd; }
        run += bf2f(v4[q2]);
      }
    }
    atomicAdd(&sums[(size_t)cur*256 + c], run);
  }
}

// ======== fused node MLP1 + MLP2 (64-row tiles, 256 threads / 4 waves, 314 blocks) ========
__global__ __launch_bounds__(256, 4)
void gemm_node12(const UST* __restrict__ h, const float* __restrict__ sums,
                 const int* __restrict__ offs, const UST* __restrict__ B1,
                 const float* __restrict__ bn1, const UST* __restrict__ B2,
                 const float* __restrict__ bn2,
                 float* __restrict__ out_f, const float* __restrict__ resid){
  __shared__ __attribute__((aligned(16))) UST lds[20480];  // 40KB union
  UST* As0 = lds;             // [64][32]
  UST* As1 = lds + 2048;
  UST* Bs0 = lds + 4096;      // [256][32]
  UST* Bs1 = lds + 12288;
  UST* y1t = lds;             // [64][264]
  int t = threadIdx.x;
  int bM = blockIdx.x;
  int rA = t >> 2, cA = (t & 3) * 8;
  int row = bM*64 + rA;
  bool valid = row < N_NODES;
  float inv = 0.0f;
  if (valid){
    int deg = offs[row+1] - offs[row];
    inv = 1.0f / fmaxf((float)deg, 1.0f);
  }
  const UST* hrow = h + (size_t)row*256;
  const float* srow = sums + (size_t)row*256;
  int lane = t & 63, lm = lane & 15, quad = lane >> 4;
  int wave = t >> 6, wN = wave*64;
  floatx4 acc[4][4] = {};
  UST* a0d = &As0[rA*32 + cA];
  UST* a1d = &As1[rA*32 + cA];
  const uint4 z4 = {0,0,0,0};
#pragma unroll 1
  for (int w = 0; w < 8; ++w){
    int k0 = w*64;
    if (k0 < 256){                      // h half via async copy
      if (valid){
        gll16(hrow + k0 + cA,      a0d);
        gll16(hrow + k0 + 32 + cA, a1d);
      } else {
        *(uint4*)a0d = z4;
        *(uint4*)a1d = z4;
      }
    } else {                            // agg half built from sums/deg
      uint4 o0 = z4, o1 = z4;
      if (valid){
        int q = k0 - 256 + cA;
        float4 s0 = *(const float4*)(srow + q);
        float4 s1 = *(const float4*)(srow + q + 4);
        o0.x = cvtpk(s0.x*inv, s0.y*inv); o0.y = cvtpk(s0.z*inv, s0.w*inv);
        o0.z = cvtpk(s1.x*inv, s1.y*inv); o0.w = cvtpk(s1.z*inv, s1.w*inv);
        float4 s2 = *(const float4*)(srow + q + 32);
        float4 s3 = *(const float4*)(srow + q + 36);
        o1.x = cvtpk(s2.x*inv, s2.y*inv); o1.y = cvtpk(s2.z*inv, s2.w*inv);
        o1.z = cvtpk(s3.x*inv, s3.y*inv); o1.w = cvtpk(s3.z*inv, s3.w*inv);
      }
      *(uint4*)a0d = o0;
      *(uint4*)a1d = o1;
    }
#pragma unroll
    for (int j = 0; j < 4; ++j){
      int rB = j*64 + rA;
      gll16(B1 + (size_t)rB*512 + k0 + cA,      &Bs0[rB*32 + cA]);
      gll16(B1 + (size_t)rB*512 + k0 + 32 + cA, &Bs1[rB*32 + cA]);
    }
    __syncthreads();
    mfma_step(As0, Bs0, acc, lm, quad, 0, wN);
    mfma_step(As1, Bs1, acc, lm, quad, 0, wN);
    __syncthreads();
  }
  // epilogue 1: silu -> y1t (packed pairs over r)
#pragma unroll
  for (int mi = 0; mi < 4; ++mi){
    int ml0 = mi*16 + quad*4;
#pragma unroll
    for (int ni = 0; ni < 4; ++ni){
      int nl = wN + ni*16 + lm;
      float b = bn1[nl];
      unsigned w01 = cvtpk(siluf(acc[mi][ni][0] + b), siluf(acc[mi][ni][1] + b));
      unsigned w23 = cvtpk(siluf(acc[mi][ni][2] + b), siluf(acc[mi][ni][3] + b));
      y1t[(ml0+0)*264 + nl] = (UST)(w01 & 0xffffu);
      y1t[(ml0+1)*264 + nl] = (UST)(w01 >> 16);
      y1t[(ml0+2)*264 + nl] = (UST)(w23 & 0xffffu);
      y1t[(ml0+3)*264 + nl] = (UST)(w23 >> 16);
    }
  }
  __syncthreads();
  // phase 2: barrier-free
  floatx4 acc2[4][4] = {};
  mfma_direct(y1t, 264, B2, 256, 256, acc2, lm, quad, 0, wN);
  int mbase = bM*64 + quad*4;
  int nbase = wN + lm;
#pragma unroll
  for (int mi = 0; mi < 4; ++mi)
#pragma unroll
    for (int r = 0; r < 4; ++r){
      int m = mbase + mi*16 + r;
      if (m < N_NODES){
#pragma unroll
        for (int ni = 0; ni < 4; ++ni){
          int n = nbase + ni*16;
          float v = siluf(acc2[mi][ni][r] + bn2[n]);
          out_f[(size_t)m*256 + n] = resid[(size_t)m*256 + n] + v;
        }
      }
    }
}

extern "C" void kernel_launch(void* const* d_in, const int* in_sizes, int n_in,
                              void* d_out, int out_size, void* d_ws, size_t ws_size,
                              hipStream_t stream){
  (void)in_sizes; (void)n_in; (void)out_size; (void)ws_size;
  const float* node_features = (const float*)d_in[0];
  const float* lattices      = (const float*)d_in[1];
  const int*   edge_index    = (const int*)d_in[2];   // [2,E]: row0=src, row1=dst
  const int*   edge2graph    = (const int*)d_in[3];
  const float* frac_diff     = (const float*)d_in[4];
  const float* ln_gamma      = (const float*)d_in[6];
  const float* ln_beta       = (const float*)d_in[7];
  const float* We1 = (const float*)d_in[8];
  const float* be1 = (const float*)d_in[9];
  const float* We2 = (const float*)d_in[10];
  const float* be2 = (const float*)d_in[11];
  const float* Wn1 = (const float*)d_in[12];
  const float* bn1 = (const float*)d_in[13];
  const float* Wn2 = (const float*)d_in[14];
  const float* bn2 = (const float*)d_in[15];

  char* w = (char*)d_ws;
  size_t off_b = 0;
  auto carve = [&](size_t bytes) -> char* {
    char* p = w + off_b; off_b += (bytes + 1023) & ~(size_t)1023; return p;
  };
  UST*   W1T  = (UST*)carve((size_t)256*KF*2);
  UST*   W2T  = (UST*)carve((size_t)256*256*2);
  UST*   Wn1T = (UST*)carve((size_t)256*512*2);
  UST*   Wn2T = (UST*)carve((size_t)256*256*2);
  UST*   W1hT = (UST*)carve((size_t)512*256*2);
  UST*   hbf  = (UST*)carve((size_t)M_PAD*256*2);      // padded rows for gemm_p1
  UST*   P1   = (UST*)carve((size_t)M_PAD*512*2);      // [node][hi | hj] bf16, fragment cols
  float* Pleb = (float*)carve((size_t)1000*256*4);     // le contribution + be1, fp32, frag cols
  int*   cnti = (int*)carve((size_t)20480*4);          // padded for int4 scan
  int*   offs = (int*)carve((size_t)(N_NODES+1)*4);
  int*   head = (int*)carve((size_t)N_NODES*4);
  int*   eidx = (int*)carve((size_t)E_EDGES*4);
  int*   srcs = (int*)carve((size_t)E_EDGES*4);        // sorted src per CSR slot
  float* sums = (float*)carve((size_t)N_NODES*256*4);

  hipMemsetAsync(cnti, 0, (size_t)20480*4, stream);
  hipMemsetAsync(sums, 0, (size_t)N_NODES*256*4, stream);

  prep_all<<<7664 + E_EDGES/256, 256, 0, stream>>>(We1, We2, Wn1, Wn2,
      node_features, ln_gamma, ln_beta, lattices, edge_index, be1, cnti,
      W1T, W2T, Wn1T, Wn2T, W1hT, hbf, Pleb);

  scan_kernel<<<1, 256, 0, stream>>>(cnti, offs, head);
  fill_kernel<<<E_EDGES/256, 256, 0, stream>>>(edge_index, head, eidx, srcs);

  gemm_p1<<<(M_PAD/64)*2, 256, 0, stream>>>(hbf, W1hT, P1);

  gemm_edge_fused<<<E_EDGES/128, 512, 0, stream>>>(
      edge_index, edge2graph, frac_diff, W1T, eidx, W2T, be2, srcs, P1, Pleb, sums);

  gemm_node12<<<M_PAD/64, 256, 0, stream>>>(
      hbf, sums, offs, Wn1T, bn1, Wn2T, bn2, (float*)d_out, node_features);
}